// Round 10
// baseline (258.820 us; speedup 1.0000x reference)
//
#include <hip/hip_runtime.h>

#define BB 2
#define SS 2048
#define DD 1024
#define NH 16
#define NKVH 4
#define HD 64
#define QKVN 1536          // fused Wqkv output columns: 1024 q | 256 k | 256 v
#define SCALE 0.125f       // 64^-0.5, exact power of 2 -> folded into Q frags

typedef __bf16 bf16;
typedef __bf16 bf16x4 __attribute__((ext_vector_type(4)));
typedef __bf16 bf16x8 __attribute__((ext_vector_type(8)));
typedef float floatx4 __attribute__((ext_vector_type(4)));

#define ASYNC16(gp, lp) __builtin_amdgcn_global_load_lds(                      \
    (const __attribute__((address_space(1))) unsigned int*)(gp),               \
    (__attribute__((address_space(3))) unsigned int*)(lp), 16, 0, 0)

// ---------- prep: LDS-tiled weight transposes + hs cast ----------
__global__ __launch_bounds__(256) void prep_kernel(const float* __restrict__ hs,
                                                   const float* __restrict__ Wq,
                                                   const float* __restrict__ Wk,
                                                   const float* __restrict__ Wv,
                                                   const float* __restrict__ Wo,
                                                   bf16* __restrict__ hsb,
                                                   bf16* __restrict__ WqkvT,
                                                   bf16* __restrict__ WoT) {
    __shared__ bf16 tl[64 * 66];
    int bidx = blockIdx.x, t = threadIdx.x;
    const int NT_QKV = 16 * 24;    // K/64 x QKVN/64
    const int NT_WO  = 16 * 16;
    if (bidx < NT_QKV + NT_WO) {
        int k0, n0, stride;
        const float* src;
        bf16* dst;
        if (bidx < NT_QKV) {
            int tk = bidx / 24, tn = bidx - tk * 24;
            k0 = tk * 64; n0 = tn * 64;
            if (n0 < 1024)      { src = Wq + n0;          stride = 1024; }
            else if (n0 < 1280) { src = Wk + (n0 - 1024); stride = 256;  }
            else                { src = Wv + (n0 - 1280); stride = 256;  }
            dst = WqkvT + (size_t)n0 * DD + k0;
        } else {
            int j = bidx - NT_QKV;
            int tk = j >> 4, tn = j & 15;
            k0 = tk * 64; n0 = tn * 64;
            src = Wo + n0; stride = 1024;
            dst = WoT + (size_t)n0 * DD + k0;
        }
        int c = t & 63, r0 = (t >> 6) * 16;
        for (int j = 0; j < 16; ++j)
            tl[c * 66 + r0 + j] = (bf16)src[(size_t)(k0 + r0 + j) * stride + c];
        __syncthreads();
        for (int j = 0; j < 16; ++j)
            dst[(size_t)(r0 + j) * DD + c] = tl[(r0 + j) * 66 + c];
    } else {
        int i = (bidx - (NT_QKV + NT_WO)) * 256 + t;   // n4 = 1048576 exactly
        float4 v = ((const float4*)hs)[i];
        ((bf16x4*)hsb)[i] = bf16x4{(bf16)v.x, (bf16)v.y, (bf16)v.z, (bf16)v.w};
    }
}

// ---------- QKV GEMM (128x64 tile) with fused RoPE + scatter epilogue ----------
__global__ __launch_bounds__(256) void gemm_qkv(const bf16* __restrict__ A,
                                                const bf16* __restrict__ Bt,
                                                const float* __restrict__ cosb,
                                                const float* __restrict__ sinb,
                                                bf16* __restrict__ Qr,
                                                bf16* __restrict__ Kr,
                                                bf16* __restrict__ Vt) {
    __shared__ bf16 As[128 * 32];
    __shared__ bf16 Bs[64 * 32];
    int t = threadIdx.x;
    int wave = t >> 6, lane = t & 63;
    int lm = lane & 15, quad = lane >> 4;
    int m0 = blockIdx.x * 128, n0 = blockIdx.y * 64;
    int wr = wave >> 1, wc = wave & 1;      // 64m x 32n per wave
    const int K = DD;

    int srow = t >> 2;                      // 0..63
    int scol = (t & 3) * 8;
    const bf16* ga = A  + (size_t)(m0 + srow) * K + scol;
    const bf16* gb = Bt + (size_t)(n0 + srow) * K + scol;
    bf16* la0 = &As[wave * 512];
    bf16* lb0 = &Bs[wave * 512];

    floatx4 acc[4][2];
    for (int i = 0; i < 4; ++i)
        for (int j = 0; j < 2; ++j) acc[i][j] = floatx4{0.f, 0.f, 0.f, 0.f};

    for (int ks = 0; ks < K; ks += 32) {
        __syncthreads();
        ASYNC16(ga + ks,                la0);
        ASYNC16(ga + ks + (size_t)64*K, la0 + 2048);
        ASYNC16(gb + ks,                lb0);
        __syncthreads();
        bf16x8 af[4], bfr[2];
        for (int mi = 0; mi < 4; ++mi)
            af[mi] = *(const bf16x8*)&As[(wr * 64 + mi * 16 + lm) * 32 + quad * 8];
        for (int ni = 0; ni < 2; ++ni)
            bfr[ni] = *(const bf16x8*)&Bs[(wc * 32 + ni * 16 + lm) * 32 + quad * 8];
        for (int mi = 0; mi < 4; ++mi)
            for (int ni = 0; ni < 2; ++ni)
                acc[mi][ni] = __builtin_amdgcn_mfma_f32_16x16x32_bf16(af[mi], bfr[ni],
                                                                      acc[mi][ni], 0, 0, 0);
    }
    bool odd = lm & 1;
    for (int mi = 0; mi < 4; ++mi)
        for (int ni = 0; ni < 2; ++ni) {
            int c0 = n0 + wc * 32 + ni * 16;
            int row0 = m0 + wr * 64 + mi * 16 + quad * 4;
            floatx4 a = acc[mi][ni];
            int d = (c0 & 63) + lm;
            if (c0 < 1280) {               // Q or K: apply RoPE
                int ii = d >> 1;
                for (int r = 0; r < 4; ++r) {
                    int row = row0 + r;
                    float self = a[r];
                    float part = __shfl_xor(self, 1);
                    float cc = cosb[(size_t)row * 32 + ii];
                    float sn = sinb[(size_t)row * 32 + ii];
                    float outv = odd ? fmaf(part, sn, self * cc)
                                     : fmaf(self, cc, -part * sn);
                    int s = row & (SS - 1), b = row >> 11;
                    if (c0 < 1024) {
                        int h = c0 >> 6;
                        Qr[((size_t)(b * NH + h) * SS + s) * HD + d] = (bf16)outv;
                    } else {
                        int kvh = (c0 - 1024) >> 6;
                        Kr[((size_t)(b * NKVH + kvh) * SS + s) * HD + d] = (bf16)outv;
                    }
                }
            } else {                       // V: transposed packed store
                int kvh = (c0 - 1280) >> 6;
                bf16x4 pk = {(bf16)a[0], (bf16)a[1], (bf16)a[2], (bf16)a[3]};
                int s0 = row0 & (SS - 1), b = row0 >> 11;
                *(bf16x4*)&Vt[((size_t)(b * NKVH + kvh) * HD + d) * SS + s0] = pk;
            }
        }
}

// ---------- O-projection GEMM (128x64 tile, fp32 out) ----------
__global__ __launch_bounds__(256) void gemm_out(const bf16* __restrict__ A,
                                                const bf16* __restrict__ Bt,
                                                float* __restrict__ Cf,
                                                int M, int N, int K) {
    __shared__ bf16 As[128 * 32];
    __shared__ bf16 Bs[64 * 32];
    int t = threadIdx.x;
    int wave = t >> 6, lane = t & 63;
    int lm = lane & 15, quad = lane >> 4;
    int m0 = blockIdx.x * 128, n0 = blockIdx.y * 64;
    int wr = wave >> 1, wc = wave & 1;

    int srow = t >> 2;
    int scol = (t & 3) * 8;
    const bf16* ga = A  + (size_t)(m0 + srow) * K + scol;
    const bf16* gb = Bt + (size_t)(n0 + srow) * K + scol;
    bf16* la0 = &As[wave * 512];
    bf16* lb0 = &Bs[wave * 512];

    floatx4 acc[4][2];
    for (int i = 0; i < 4; ++i)
        for (int j = 0; j < 2; ++j) acc[i][j] = floatx4{0.f, 0.f, 0.f, 0.f};

    for (int ks = 0; ks < K; ks += 32) {
        __syncthreads();
        ASYNC16(ga + ks,                la0);
        ASYNC16(ga + ks + (size_t)64*K, la0 + 2048);
        ASYNC16(gb + ks,                lb0);
        __syncthreads();
        bf16x8 af[4], bfr[2];
        for (int mi = 0; mi < 4; ++mi)
            af[mi] = *(const bf16x8*)&As[(wr * 64 + mi * 16 + lm) * 32 + quad * 8];
        for (int ni = 0; ni < 2; ++ni)
            bfr[ni] = *(const bf16x8*)&Bs[(wc * 32 + ni * 16 + lm) * 32 + quad * 8];
        for (int mi = 0; mi < 4; ++mi)
            for (int ni = 0; ni < 2; ++ni)
                acc[mi][ni] = __builtin_amdgcn_mfma_f32_16x16x32_bf16(af[mi], bfr[ni],
                                                                      acc[mi][ni], 0, 0, 0);
    }
    for (int mi = 0; mi < 4; ++mi)
        for (int ni = 0; ni < 2; ++ni)
            for (int r = 0; r < 4; ++r) {
                size_t row = (size_t)(m0 + wr * 64 + mi * 16 + quad * 4 + r);
                Cf[row * N + n0 + wc * 32 + ni * 16 + lm] = acc[mi][ni][r];
            }
}

// ---------- flash attention: barrier-free, direct-L2 K/V fragments ----------
// K+V per (b,kvh) = 2 MB, L2-resident via bid&7 XCD pin -> read fragments
// straight from global (no LDS staging, no __syncthreads anywhere).
// Wave = 16 queries, processes tile pair {pi, 127-pi} sequentially:
// (pi>>2)+1 + ((127-pi)>>2)+1 = 33 chunks for EVERY wave -> perfect balance,
// waves fully independent -> natural cross-chunk load/MFMA pipelining.
__global__ __launch_bounds__(256) void attn_kernel(const bf16* __restrict__ Qr,
                                                   const bf16* __restrict__ Kr,
                                                   const bf16* __restrict__ Vt,
                                                   bf16* __restrict__ ctx) {
    __shared__ __align__(16) bf16 p_lds[4][16][72];   // wave-private P transform
    int t = threadIdx.x;
    int wave = t >> 6, lane = t & 63;
    int lm = lane & 15, quad = lane >> 4;

    int bid = blockIdx.x;
    int grp = bid & 7;                 // XCD group = b*4 + kvh
    int b = grp >> 2, kvh = grp & 3;
    int wid = (bid >> 3) * 4 + wave;   // 0..255 within group
    int h = kvh * 4 + (wid & 3);
    int pi = wid >> 2;                 // 0..63 -> tile pair {pi, 127-pi}

    const bf16* kbase = Kr + (size_t)(b * NKVH + kvh) * SS * HD;
    const bf16* vbase = Vt + (size_t)(b * NKVH + kvh) * HD * SS;
    const bf16* qhead = Qr + (size_t)(b * NH + h) * SS * HD;
    bf16* chead = ctx + (size_t)b * SS * DD + h * HD;

    for (int pass = 0; pass < 2; ++pass) {
        int tile = pass ? (127 - pi) : pi;
        int q0w = tile * 16;
        int nch = (tile >> 2) + 1;

        // Q fragments, pre-scaled by SCALE (0.125 = 2^-3, exact in bf16)
        const bf16* qp = qhead + (size_t)(q0w + lm) * HD;
        bf16x8 qf0 = *(const bf16x8*)(qp + quad * 8);
        bf16x8 qf1 = *(const bf16x8*)(qp + 32 + quad * 8);
        for (int e = 0; e < 8; ++e) {
            qf0[e] = (bf16)((float)qf0[e] * SCALE);
            qf1[e] = (bf16)((float)qf1[e] * SCALE);
        }

        float m_prev = -1e30f, l_prev = 0.f;
        floatx4 o[4];
        for (int dt = 0; dt < 4; ++dt) o[dt] = floatx4{0.f, 0.f, 0.f, 0.f};

        for (int ck = 0; ck < nch; ++ck) {
            int kb = ck * 64;
            // S^T = K·Q^T; K fragments direct from L2
            floatx4 st[4];
            for (int tt = 0; tt < 4; ++tt) {
                const bf16* krow = kbase + (size_t)(kb + tt * 16 + lm) * HD;
                bf16x8 k0 = *(const bf16x8*)(krow + quad * 8);
                bf16x8 k1 = *(const bf16x8*)(krow + 32 + quad * 8);
                floatx4 s = {0.f, 0.f, 0.f, 0.f};
                s = __builtin_amdgcn_mfma_f32_16x16x32_bf16(k0, qf0, s, 0, 0, 0);
                s = __builtin_amdgcn_mfma_f32_16x16x32_bf16(k1, qf1, s, 0, 0, 0);
                st[tt] = s;
            }
            if (ck == nch - 1) {                   // causal mask (diag chunk only)
                for (int tt = 0; tt < 4; ++tt)
                    for (int r = 0; r < 4; ++r)
                        if (kb + tt * 16 + quad * 4 + r > q0w + lm) st[tt][r] = -1e30f;
            }
            // tree max over 16 regs + 2 quad shuffles
            float tm[4];
            for (int tt = 0; tt < 4; ++tt)
                tm[tt] = fmaxf(fmaxf(st[tt][0], st[tt][1]), fmaxf(st[tt][2], st[tt][3]));
            float mx = fmaxf(fmaxf(tm[0], tm[1]), fmaxf(tm[2], tm[3]));
            mx = fmaxf(mx, __shfl_xor(mx, 16));
            mx = fmaxf(mx, __shfl_xor(mx, 32));
            float m_new = fmaxf(m_prev, mx);
            float alpha = __expf(m_prev - m_new);
            m_prev = m_new;
            float ts[4];
            for (int tt = 0; tt < 4; ++tt) {
                float p0 = __expf(st[tt][0] - m_new);
                float p1 = __expf(st[tt][1] - m_new);
                float p2 = __expf(st[tt][2] - m_new);
                float p3 = __expf(st[tt][3] - m_new);
                st[tt] = floatx4{p0, p1, p2, p3};
                ts[tt] = (p0 + p1) + (p2 + p3);
            }
            float ls = (ts[0] + ts[1]) + (ts[2] + ts[3]);
            ls += __shfl_xor(ls, 16);
            ls += __shfl_xor(ls, 32);
            l_prev = l_prev * alpha + ls;

            // P^T -> A-layout via wave-private LDS (in-wave lgkmcnt only)
            for (int tt = 0; tt < 4; ++tt) {
                bf16x4 pk = {(bf16)st[tt][0], (bf16)st[tt][1],
                             (bf16)st[tt][2], (bf16)st[tt][3]};
                *(bf16x4*)&p_lds[wave][lm][tt * 16 + quad * 4] = pk;
            }
            for (int r = 0; r < 4; ++r) {
                float a = __shfl(alpha, quad * 4 + r);
                for (int dt = 0; dt < 4; ++dt) o[dt][r] *= a;
            }
            bf16x8 pa0 = *(const bf16x8*)&p_lds[wave][lm][quad * 8];
            bf16x8 pa1 = *(const bf16x8*)&p_lds[wave][lm][32 + quad * 8];
            // O += P V; V fragments direct from L2
            for (int dt = 0; dt < 4; ++dt) {
                const bf16* vrow = vbase + (size_t)(dt * 16 + lm) * SS + kb;
                bf16x8 v0 = *(const bf16x8*)(vrow + quad * 8);
                bf16x8 v1 = *(const bf16x8*)(vrow + 32 + quad * 8);
                o[dt] = __builtin_amdgcn_mfma_f32_16x16x32_bf16(pa0, v0, o[dt], 0, 0, 0);
                o[dt] = __builtin_amdgcn_mfma_f32_16x16x32_bf16(pa1, v1, o[dt], 0, 0, 0);
            }
        }
        float linv = 1.f / l_prev;
        for (int r = 0; r < 4; ++r) {
            float inv = __shfl(linv, quad * 4 + r);
            int qi = q0w + quad * 4 + r;
            for (int dt = 0; dt < 4; ++dt)
                chead[(size_t)qi * DD + dt * 16 + lm] = (bf16)(o[dt][r] * inv);
        }
    }
}

// ---------- host ----------
extern "C" void kernel_launch(void* const* d_in, const int* in_sizes, int n_in,
                              void* d_out, int out_size, void* d_ws, size_t ws_size,
                              hipStream_t stream) {
    const float* hs   = (const float*)d_in[0];
    const float* cosb = (const float*)d_in[1];
    const float* sinb = (const float*)d_in[2];
    const float* Wq = (const float*)d_in[4];
    const float* Wk = (const float*)d_in[5];
    const float* Wv = (const float*)d_in[6];
    const float* Wo = (const float*)d_in[7];
    float* out = (float*)d_out;

    char* ws = (char*)d_ws;
    size_t off = 0;
    auto alloc = [&](size_t bytes) {
        char* p = ws + off;
        off += (bytes + 255) & ~(size_t)255;
        return p;
    };
    const size_t MT = (size_t)BB * SS;                    // 4096 tokens
    bf16* hsb     = (bf16*)alloc(MT * DD * 2);
    bf16* WqkvT   = (bf16*)alloc((size_t)QKVN * DD * 2);
    bf16* WoT     = (bf16*)alloc((size_t)DD * DD * 2);
    bf16* Qr      = (bf16*)alloc(MT * DD * 2);
    bf16* Kr      = (bf16*)alloc(MT * 256 * 2);
    bf16* Vt      = (bf16*)alloc(MT * 256 * 2);
    bf16* ctx     = (bf16*)alloc(MT * DD * 2);

    // 1. prep: tiled weight transposes + hs cast
    prep_kernel<<<384 + 256 + 4096, 256, 0, stream>>>(hs, Wq, Wk, Wv, Wo,
                                                      hsb, WqkvT, WoT);
    // 2. fused QKV projection + RoPE + V scatter (768 blocks = 3/CU)
    gemm_qkv<<<dim3(MT / 128, QKVN / 64), 256, 0, stream>>>(hsb, WqkvT, cosb, sinb,
                                                            Qr, Kr, Vt);
    // 3. attention (512 WGs x 4 indep waves; bid&7 = XCD group; 33 chunks/wave)
    attn_kernel<<<512, 256, 0, stream>>>(Qr, Kr, Vt, ctx);
    // 4. output projection (512 blocks = 2/CU, fp32 out)
    gemm_out<<<dim3(MT / 128, DD / 64), 256, 0, stream>>>(ctx, WoT, out,
                                                          (int)MT, DD, DD);

    (void)in_sizes; (void)n_in; (void)out_size; (void)ws_size;
}